// Round 1
// baseline (836.871 us; speedup 1.0000x reference)
//
#include <hip/hip_runtime.h>
#include <math.h>

// Problem constants (from reference):
//   N_OBJ=2048, IN_DIM=128, MID_DIM=256, OUT_DIM=1
// Per-object 3-layer MLP (grouped GEMV). Memory-bound: ~773 MB of weights
// streamed once per call -> roofline ~123 us @ 6.3 TB/s.

#define N_OBJ   2048
#define IN_DIM  128
#define MID_DIM 256

__global__ __launch_bounds__(256, 8) void mlp_grouped_kernel(
    const float* __restrict__ x,   // [O, 128]
    const float* __restrict__ W1,  // [O, 256, 128]
    const float* __restrict__ b1,  // [O, 256]
    const float* __restrict__ W2,  // [O, 256, 256]
    const float* __restrict__ b2,  // [O, 256]
    const float* __restrict__ W3,  // [O, 1, 256]
    const float* __restrict__ b3,  // [O, 1]
    float* __restrict__ out)       // [O]
{
    const int o = blockIdx.x;
    const int t = threadIdx.x;

    __shared__ __align__(16) float s_x[IN_DIM];
    __shared__ __align__(16) float s_y1[MID_DIM];
    __shared__ __align__(16) float s_y2[MID_DIM];
    __shared__ float s_red[4];

    // Stage x[o,:] into LDS (coalesced 512 B).
    if (t < IN_DIM) s_x[t] = x[(size_t)o * IN_DIM + t];
    __syncthreads();

    // ----- Layer 1: y1[t] = dot(x, W1[o,t,:]) + b1[o,t]   (NO activation) -----
    {
        const float4* w = (const float4*)(W1 + (size_t)o * MID_DIM * IN_DIM
                                             + (size_t)t * IN_DIM);
        const float4* xv = (const float4*)s_x;
        float acc = 0.0f;
        #pragma unroll 8
        for (int j = 0; j < IN_DIM / 4; ++j) {
            float4 wv = w[j];
            float4 v  = xv[j];
            acc += wv.x * v.x + wv.y * v.y + wv.z * v.z + wv.w * v.w;
        }
        s_y1[t] = acc + b1[(size_t)o * MID_DIM + t];
    }
    __syncthreads();

    // ----- Layer 2: y2[t] = sigmoid(dot(y1, W2[o,t,:]) + b2[o,t]) -----
    {
        const float4* w = (const float4*)(W2 + (size_t)o * MID_DIM * MID_DIM
                                             + (size_t)t * MID_DIM);
        const float4* yv = (const float4*)s_y1;
        float acc = 0.0f;
        #pragma unroll 8
        for (int j = 0; j < MID_DIM / 4; ++j) {
            float4 wv = w[j];
            float4 v  = yv[j];
            acc += wv.x * v.x + wv.y * v.y + wv.z * v.z + wv.w * v.w;
        }
        acc += b2[(size_t)o * MID_DIM + t];
        s_y2[t] = 1.0f / (1.0f + expf(-acc));
    }
    __syncthreads();

    // ----- Layer 3: out[o] = sigmoid(dot(y2, W3[o,0,:]) + b3[o]) -----
    {
        float p = s_y2[t] * W3[(size_t)o * MID_DIM + t];
        // wave64 butterfly reduce
        #pragma unroll
        for (int off = 32; off > 0; off >>= 1)
            p += __shfl_down(p, off, 64);
        if ((t & 63) == 0) s_red[t >> 6] = p;
        __syncthreads();
        if (t == 0) {
            float s = s_red[0] + s_red[1] + s_red[2] + s_red[3]
                    + b3[o];
            out[o] = 1.0f / (1.0f + expf(-s));
        }
    }
}

extern "C" void kernel_launch(void* const* d_in, const int* in_sizes, int n_in,
                              void* d_out, int out_size, void* d_ws, size_t ws_size,
                              hipStream_t stream) {
    const float* x  = (const float*)d_in[0];
    const float* W1 = (const float*)d_in[1];
    const float* b1 = (const float*)d_in[2];
    const float* W2 = (const float*)d_in[3];
    const float* b2 = (const float*)d_in[4];
    const float* W3 = (const float*)d_in[5];
    const float* b3 = (const float*)d_in[6];
    float* out = (float*)d_out;

    mlp_grouped_kernel<<<N_OBJ, 256, 0, stream>>>(x, W1, b1, W2, b2, W3, b3, out);
}